// Round 7
// baseline (281.090 us; speedup 1.0000x reference)
//
#include <hip/hip_runtime.h>
#include <hip/hip_bf16.h>
#include <cstdint>
#include <cstddef>

#define N_NODES 50000
#define NEG_SLOPE 0.2f
#define NB 196            // buckets of 256 nodes: (50000+255)/256
#define BIN_CHUNK 8192    // edges per block in hist/bin kernels
#define SLICE_MAX 14336   // LDS slice capacity (mean ~4345, 3.3x headroom)

typedef float floatx4 __attribute__((ext_vector_type(4)));
typedef short shortx8 __attribute__((ext_vector_type(8)));

// ---- fp32 <-> bf16 helpers (RNE) --------------------------------------------
__device__ __forceinline__ unsigned short f2b(float f) {
    union { float f; unsigned u; } v; v.f = f;
    unsigned u = v.u;
    return (unsigned short)((u + 0x7FFFu + ((u >> 16) & 1u)) >> 16);
}
__device__ __forceinline__ float b2f(unsigned short b) {
    union { unsigned u; float f; } v; v.u = ((unsigned)b) << 16;
    return v.f;
}

// ---------------------------------------------------------------------------
// CSR build, bucketed multisplit.
// ---------------------------------------------------------------------------
__global__ __launch_bounds__(256) void bucket_hist_kernel(
    const int* __restrict__ ei, int E0, int E, int* __restrict__ bhist) {
    __shared__ int h[NB];
    int t = threadIdx.x;
    for (int i = t; i < NB; i += 256) h[i] = 0;
    __syncthreads();
    int base = blockIdx.x * BIN_CHUNK;
    int end = min(base + BIN_CHUNK, E);
    for (int e = base + t; e < end; e += 256) {
        int d = (e < E0) ? ei[E0 + e] : (e - E0);
        atomicAdd(&h[d >> 8], 1);
    }
    __syncthreads();
    for (int i = t; i < NB; i += 256)
        if (h[i]) atomicAdd(&bhist[i], h[i]);
}

__global__ __launch_bounds__(256) void bucket_scan_kernel(
    const int* __restrict__ bhist, int* __restrict__ bbase,
    int* __restrict__ bcursor, int* __restrict__ rowptr, int E) {
    __shared__ int buf[256];
    int t = threadIdx.x;
    int v = (t < NB) ? bhist[t] : 0;
    int x = v;
    for (int off = 1; off < 256; off <<= 1) {
        buf[t] = x; __syncthreads();
        int y = (t >= off) ? buf[t - off] : 0;
        __syncthreads();
        x += y;
    }
    if (t < NB) {
        bbase[t] = x - v;
        bcursor[t] = x - v;
    }
    if (t == NB - 1) bbase[NB] = x;
    if (t == 0) rowptr[N_NODES] = E;
}

__global__ __launch_bounds__(256) void bin_kernel(
    const int* __restrict__ ei, int E0, int E,
    int* __restrict__ bcursor, unsigned int* __restrict__ ebuf) {
    __shared__ int h[NB];
    __shared__ int gbase[NB];
    int t = threadIdx.x;
    for (int i = t; i < NB; i += 256) h[i] = 0;
    __syncthreads();
    int base = blockIdx.x * BIN_CHUNK;
    int end = min(base + BIN_CHUNK, E);
    for (int e = base + t; e < end; e += 256) {
        int d = (e < E0) ? ei[E0 + e] : (e - E0);
        atomicAdd(&h[d >> 8], 1);
    }
    __syncthreads();
    for (int i = t; i < NB; i += 256) {
        int c = h[i];
        gbase[i] = c ? atomicAdd(&bcursor[i], c) : 0;
        h[i] = 0;
    }
    __syncthreads();
    for (int e = base + t; e < end; e += 256) {
        int s, d;
        if (e < E0) { s = ei[e]; d = ei[E0 + e]; }
        else        { s = e - E0; d = e - E0; }
        int b = d >> 8;
        int off = atomicAdd(&h[b], 1);
        ebuf[gbase[b] + off] = (unsigned)s | ((unsigned)(d & 255) << 16);
    }
}

// K4: one block per bucket; emits rowptr, csr_src (int) and csr_dst (ushort)
__global__ __launch_bounds__(256) void build_kernel(
    const unsigned int* __restrict__ ebuf, const int* __restrict__ bbase,
    int* __restrict__ rowptr, int* __restrict__ csr_src,
    unsigned short* __restrict__ csr_dst) {
    __shared__ int h[256];
    __shared__ int lrp[257];
    __shared__ unsigned int stag[SLICE_MAX];
    int b = blockIdx.x, t = threadIdx.x;
    int e0 = bbase[b], e1 = bbase[b + 1];
    int cnt = e1 - e0;
    int n0 = b << 8;
    h[t] = 0;
    __syncthreads();
    for (int i = t; i < cnt; i += 256)
        atomicAdd(&h[ebuf[e0 + i] >> 16], 1);
    __syncthreads();
    int v = h[t], x = v;
    __shared__ int buf[256];
    for (int off = 1; off < 256; off <<= 1) {
        buf[t] = x; __syncthreads();
        int y = (t >= off) ? buf[t - off] : 0;
        __syncthreads();
        x += y;
    }
    lrp[t] = x - v;
    if (t == 255) lrp[256] = x;
    h[t] = 0;
    __syncthreads();
    int n = n0 + t;
    if (n < N_NODES) rowptr[n] = e0 + lrp[t];
    for (int i = t; i < cnt; i += 256) {
        unsigned int v2 = ebuf[e0 + i];
        int dloc = v2 >> 16;
        int off = atomicAdd(&h[dloc], 1);
        stag[lrp[dloc] + off] = v2;           // src | dloc<<16 (both <2^16)
    }
    __syncthreads();
    for (int i = t; i < cnt; i += 256) {
        unsigned int v2 = stag[i];
        csr_src[e0 + i] = (int)(v2 & 0xFFFFu);
        csr_dst[e0 + i] = (unsigned short)(n0 + (v2 >> 16));
    }
}

// ---------------------------------------------------------------------------
// Edge-major attention-weight precompute.
// ---------------------------------------------------------------------------
__global__ __launch_bounds__(256) void edge_w1_kernel(
    const int* __restrict__ csr_src, const unsigned short* __restrict__ csr_dst,
    const float* __restrict__ a_src, const float* __restrict__ a_dst,
    float* __restrict__ ew, int E) {
    int e = blockIdx.x * blockDim.x + threadIdx.x;
    if (e >= E) return;
    int s = csr_src[e];
    int d = csr_dst[e];
    float4 as = *(const float4*)&a_src[s << 2];
    float4 ad = *(const float4*)&a_dst[d << 2];
    float4 w;
    float l;
    l = as.x + ad.x; l = l > 0.f ? l : NEG_SLOPE * l; w.x = __expf(l);
    l = as.y + ad.y; l = l > 0.f ? l : NEG_SLOPE * l; w.y = __expf(l);
    l = as.z + ad.z; l = l > 0.f ? l : NEG_SLOPE * l; w.z = __expf(l);
    l = as.w + ad.w; l = l > 0.f ? l : NEG_SLOPE * l; w.w = __expf(l);
    *(float4*)&ew[(size_t)e << 2] = w;
}

__global__ __launch_bounds__(256) void edge_w2_kernel(
    const int* __restrict__ csr_src, const unsigned short* __restrict__ csr_dst,
    const float* __restrict__ a_src, const float* __restrict__ a_dst,
    float* __restrict__ ew, int E) {
    int e = blockIdx.x * blockDim.x + threadIdx.x;
    if (e >= E) return;
    float l = a_src[csr_src[e]] + a_dst[csr_dst[e]];
    l = l > 0.f ? l : NEG_SLOPE * l;
    ew[e] = __expf(l);
}

// ---------------------------------------------------------------------------
// Single-bf16 MFMA GEMM:  C[M,NREAL] = A[M,KK] x B[NREAL,KK]^T
// InT: float (convert in staging) or ushort (bf16 passthrough).
// OutT: ushort (bf16) or float.
// ---------------------------------------------------------------------------
template <int BM, int BN, int NREAL, int KK, typename InT, typename OutT>
__global__ __launch_bounds__(256) void gemm_bf16_kernel(
    const InT* __restrict__ A, const float* __restrict__ B,
    OutT* __restrict__ C, int M) {
    const int BK = 64, LDK = 72;
    const int NT = BN / 16;
    __shared__ unsigned short As[BM * LDK];
    __shared__ unsigned short Bs[BN * LDK];
    const int t = threadIdx.x;
    const int wave = t >> 6, lane = t & 63;
    const int lrow = lane & 15, lkg = lane >> 4;
    const int bm = blockIdx.x * BM;

    floatx4 acc[NT] = {};

    for (int k0 = 0; k0 < KK; k0 += BK) {
        __syncthreads();
        if constexpr (sizeof(InT) == 4) {
            for (int i = t; i < BM * 16; i += 256) {
                int r = i >> 4, c4 = (i & 15) << 2;
                int gr = bm + r;
                float4 v = make_float4(0.f, 0.f, 0.f, 0.f);
                if (gr < M) v = *(const float4*)&A[(size_t)gr * KK + k0 + c4];
                int o = r * LDK + c4;
                As[o] = f2b(v.x); As[o + 1] = f2b(v.y);
                As[o + 2] = f2b(v.z); As[o + 3] = f2b(v.w);
            }
        } else {
            for (int i = t; i < BM * 8; i += 256) {
                int r = i >> 3, c8 = (i & 7) << 3;
                int gr = bm + r;
                shortx8 v = {};
                if (gr < M) v = *(const shortx8*)&A[(size_t)gr * KK + k0 + c8];
                *(shortx8*)&As[r * LDK + c8] = v;
            }
        }
        for (int i = t; i < BN * 16; i += 256) {
            int r = i >> 4, c4 = (i & 15) << 2;
            float4 v = make_float4(0.f, 0.f, 0.f, 0.f);
            if (r < NREAL) v = *(const float4*)&B[(size_t)r * KK + k0 + c4];
            int o = r * LDK + c4;
            Bs[o] = f2b(v.x); Bs[o + 1] = f2b(v.y);
            Bs[o + 2] = f2b(v.z); Bs[o + 3] = f2b(v.w);
        }
        __syncthreads();

        for (int ks = 0; ks < BK; ks += 32) {
            int kc = ks + lkg * 8;
            int row = wave * 16 + lrow;
            shortx8 a = *(const shortx8*)&As[row * LDK + kc];
#pragma unroll
            for (int nt = 0; nt < NT; nt++) {
                shortx8 b = *(const shortx8*)&Bs[(nt * 16 + lrow) * LDK + kc];
                acc[nt] = __builtin_amdgcn_mfma_f32_16x16x32_bf16(a, b, acc[nt], 0, 0, 0);
            }
        }
    }
#pragma unroll
    for (int nt = 0; nt < NT; nt++)
#pragma unroll
        for (int r = 0; r < 4; r++) {
            int row = bm + wave * 16 + lkg * 4 + r;
            int col = nt * 16 + lrow;
            if (row < M && col < NREAL) {
                if constexpr (sizeof(OutT) == 2)
                    C[(size_t)row * NREAL + col] = f2b(acc[nt][r]);
                else
                    C[(size_t)row * NREAL + col] = acc[nt][r];
            }
        }
}

// ---------------------------------------------------------------------------
// Attention coefficients
// ---------------------------------------------------------------------------
__global__ void att1_kernel(const unsigned short* __restrict__ h1b,
                            const float* __restrict__ att_src,
                            const float* __restrict__ att_dst,
                            float* __restrict__ a_src, float* __restrict__ a_dst,
                            int N) {
    int i = blockIdx.x * blockDim.x + threadIdx.x;
    if (i >= N * 4) return;
    int h = i & 3;
    const ushort4* hp = (const ushort4*)(h1b + (size_t)i * 32);
    const float4* as = (const float4*)(att_src + h * 32);
    const float4* ad = (const float4*)(att_dst + h * 32);
    float ssum = 0.f, dsum = 0.f;
#pragma unroll
    for (int j = 0; j < 8; j++) {
        ushort4 hv = hp[j];
        float4 av = as[j], dv = ad[j];
        float x0 = b2f(hv.x), x1 = b2f(hv.y), x2 = b2f(hv.z), x3 = b2f(hv.w);
        ssum += x0 * av.x + x1 * av.y + x2 * av.z + x3 * av.w;
        dsum += x0 * dv.x + x1 * dv.y + x2 * dv.z + x3 * dv.w;
    }
    a_src[i] = ssum;
    a_dst[i] = dsum;
}

// layer 2: h2 fp32 [N,40]
__global__ void att2_kernel(const float* __restrict__ h2,
                            const float* __restrict__ att_src,
                            const float* __restrict__ att_dst,
                            float* __restrict__ a_src, float* __restrict__ a_dst,
                            int N) {
    int n = blockIdx.x * blockDim.x + threadIdx.x;
    if (n >= N) return;
    const float4* hp = (const float4*)(h2 + (size_t)n * 40);
    const float4* as = (const float4*)att_src;
    const float4* ad = (const float4*)att_dst;
    float ssum = 0.f, dsum = 0.f;
#pragma unroll
    for (int j = 0; j < 10; j++) {
        float4 hv = hp[j];
        float4 av = as[j], dv = ad[j];
        ssum += hv.x * av.x + hv.y * av.y + hv.z * av.z + hv.w * av.w;
        dsum += hv.x * dv.x + hv.y * dv.y + hv.z * dv.z + hv.w * dv.w;
    }
    a_src[n] = ssum;
    a_dst[n] = dsum;
}

// ---------------------------------------------------------------------------
// Aggregation layer 1: one WAVE per node; weights read coalesced from ew.
// Guard form (no break) — every lane executes every shfl.
// ---------------------------------------------------------------------------
__global__ __launch_bounds__(256) void agg1_kernel(
    const unsigned short* __restrict__ h1b, const float* __restrict__ ew,
    const int* __restrict__ rowptr, const int* __restrict__ csr_src,
    const float* __restrict__ b1, unsigned short* __restrict__ zb, int N) {
    int wave = threadIdx.x >> 6, lane = threadIdx.x & 63;
    int n = blockIdx.x * 4 + wave;
    if (n >= N) return;
    int half = lane >> 5, pos = lane & 31, head = pos >> 3;
    int beg = rowptr[n], deg = rowptr[n + 1] - beg;

    floatx4 acc = {0.f, 0.f, 0.f, 0.f};
    float den = 0.f;
    for (int c0 = 0; c0 < deg; c0 += 16) {
        int idx = c0 + (lane >> 2);
        int s_e = (idx < deg) ? csr_src[beg + idx] : 0;
        float w_e = (idx < deg) ? ew[((size_t)(beg + c0) << 2) + lane] : 0.f;
        int cnt = min(16, deg - c0);
#pragma unroll
        for (int e = 0; e < 16; e += 2) {
            int el = e + half;
            int s = __shfl(s_e, el << 2);
            float w = __shfl(w_e, (el << 2) + head);
            if (el < cnt) {
                ushort4 v = *(const ushort4*)&h1b[(size_t)s * 128 + pos * 4];
                den += w;
                acc.x += w * b2f(v.x); acc.y += w * b2f(v.y);
                acc.z += w * b2f(v.z); acc.w += w * b2f(v.w);
            }
        }
    }
    acc.x += __shfl_xor(acc.x, 32);
    acc.y += __shfl_xor(acc.y, 32);
    acc.z += __shfl_xor(acc.z, 32);
    acc.w += __shfl_xor(acc.w, 32);
    den   += __shfl_xor(den, 32);
    if (half == 0) {
        float inv = 1.f / den;
        float4 bb = *(const float4*)&b1[pos * 4];
        float o0 = fmaxf(acc.x * inv + bb.x, 0.f);
        float o1 = fmaxf(acc.y * inv + bb.y, 0.f);
        float o2 = fmaxf(acc.z * inv + bb.z, 0.f);
        float o3 = fmaxf(acc.w * inv + bb.w, 0.f);
        ushort4 r;
        r.x = f2b(o0); r.y = f2b(o1); r.z = f2b(o2); r.w = f2b(o3);
        *(ushort4*)&zb[(size_t)n * 128 + pos * 4] = r;
    }
}

// ---------------------------------------------------------------------------
// Aggregation layer 2: one wave per node, H=1, D=40, fp32 h2.
// Round-5 structure: 32-edge batches, guard form (no break before shfl).
// ---------------------------------------------------------------------------
__global__ __launch_bounds__(256) void agg2_kernel(
    const float* __restrict__ h2, const float* __restrict__ ew,
    const int* __restrict__ rowptr, const int* __restrict__ csr_src,
    const float* __restrict__ b2, float* __restrict__ out, int N) {
    int wave = threadIdx.x >> 6, lane = threadIdx.x & 63;
    int n = blockIdx.x * 4 + wave;
    if (n >= N) return;
    int half = lane >> 5, pos = lane & 31;
    int beg = rowptr[n], deg = rowptr[n + 1] - beg;

    float2 acc = {0.f, 0.f};
    float den = 0.f;
    for (int c0 = 0; c0 < deg; c0 += 32) {
        int idx = c0 + lane;
        int s_e = 0; float w_e = 0.f;
        if (lane < 32 && idx < deg) {
            s_e = csr_src[beg + idx];
            w_e = ew[beg + idx];
        }
        int cnt = min(32, deg - c0);
#pragma unroll
        for (int e = 0; e < 32; e += 2) {
            int el = e + half;
            int s = __shfl(s_e, el);
            float w = __shfl(w_e, el);
            if (el < cnt) {
                den += w;
                if (pos < 20) {
                    float2 v = *(const float2*)&h2[(size_t)s * 40 + pos * 2];
                    acc.x += w * v.x;
                    acc.y += w * v.y;
                }
            }
        }
    }
    acc.x += __shfl_xor(acc.x, 32);
    acc.y += __shfl_xor(acc.y, 32);
    den   += __shfl_xor(den, 32);
    if (half == 0 && pos < 20) {
        float inv = 1.f / den;
        float2 bb = *(const float2*)&b2[pos * 2];
        float2 o;
        o.x = acc.x * inv + bb.x;
        o.y = acc.y * inv + bb.y;
        *(float2*)&out[(size_t)n * 40 + pos * 2] = o;
    }
}

// ---------------------------------------------------------------------------
extern "C" void kernel_launch(void* const* d_in, const int* in_sizes, int n_in,
                              void* d_out, int out_size, void* d_ws, size_t ws_size,
                              hipStream_t stream) {
    const float* x        = (const float*)d_in[0];
    const int*   ei       = (const int*)d_in[1];
    const float* W1       = (const float*)d_in[2];
    const float* att_src1 = (const float*)d_in[3];
    const float* att_dst1 = (const float*)d_in[4];
    const float* b1       = (const float*)d_in[5];
    const float* W2       = (const float*)d_in[6];
    const float* att_src2 = (const float*)d_in[7];
    const float* att_dst2 = (const float*)d_in[8];
    const float* b2       = (const float*)d_in[9];
    float* out = (float*)d_out;

    const int N  = N_NODES;
    const int E0 = in_sizes[1] / 2;
    const int E  = E0 + N;
    const int NBLK = (E + BIN_CHUNK - 1) / BIN_CHUNK;

    char* ws = (char*)d_ws;
    unsigned short* h1b = (unsigned short*)(ws + 0);          // 12,800,000
    unsigned short* zb  = (unsigned short*)(ws + 12800000);   // 12,800,000
    float*          h2  = (float*)(ws + 25600000);            //  8,000,000 (fp32)
    float* a_src1 = (float*)(ws + 33600000);                  //    800,000
    float* a_dst1 = (float*)(ws + 34400000);                  //    800,000
    float* a_src2 = (float*)(ws + 35200000);                  //    200,000
    float* a_dst2 = (float*)(ws + 35400000);                  //    200,000
    int*   rowptr = (int*)(ws + 35600000);                    //    200,004
    int*   bhist  = (int*)(ws + 35800192);                    //        784
    int*   bbase  = (int*)(ws + 35801088);                    //        788
    int*   bcursor= (int*)(ws + 35801984);                    //        784
    unsigned int* ebuf = (unsigned int*)(ws + 35802880);      //  3,400,000
    int*   csr_src= (int*)(ws + 39202880);                    //  3,400,000
    unsigned short* csr_dst = (unsigned short*)(ws + 42602880); // 1,700,000
    float* ew1    = (float*)(ws + 44302880);                  // 13,600,000
    float* ew2    = (float*)(ws + 57902880);                  //  3,400,000
    // total ~61.3 MB

    hipMemsetAsync(bhist, 0, NB * sizeof(int), stream);

    bucket_hist_kernel<<<NBLK, 256, 0, stream>>>(ei, E0, E, bhist);
    bucket_scan_kernel<<<1, 256, 0, stream>>>(bhist, bbase, bcursor, rowptr, E);
    bin_kernel<<<NBLK, 256, 0, stream>>>(ei, E0, E, bcursor, ebuf);
    build_kernel<<<NB, 256, 0, stream>>>(ebuf, bbase, rowptr, csr_src, csr_dst);

    // layer 1
    gemm_bf16_kernel<64, 128, 128, 256, float, unsigned short>
        <<<(N + 63) / 64, 256, 0, stream>>>(x, W1, h1b, N);
    att1_kernel<<<(N * 4 + 255) / 256, 256, 0, stream>>>(h1b, att_src1, att_dst1, a_src1, a_dst1, N);
    edge_w1_kernel<<<(E + 255) / 256, 256, 0, stream>>>(csr_src, csr_dst, a_src1, a_dst1, ew1, E);
    agg1_kernel<<<(N + 3) / 4, 256, 0, stream>>>(h1b, ew1, rowptr, csr_src, b1, zb, N);

    // layer 2 (h2 fp32 for accuracy headroom)
    gemm_bf16_kernel<64, 48, 40, 128, unsigned short, float>
        <<<(N + 63) / 64, 256, 0, stream>>>(zb, W2, h2, N);
    att2_kernel<<<(N + 255) / 256, 256, 0, stream>>>(h2, att_src2, att_dst2, a_src2, a_dst2, N);
    edge_w2_kernel<<<(E + 255) / 256, 256, 0, stream>>>(csr_src, csr_dst, a_src2, a_dst2, ew2, E);
    agg2_kernel<<<(N + 3) / 4, 256, 0, stream>>>(h2, ew2, rowptr, csr_src, b2, out, N);
}

// Round 8
// 279.896 us; speedup vs baseline: 1.0043x; 1.0043x over previous
//
#include <hip/hip_runtime.h>
#include <hip/hip_bf16.h>
#include <cstdint>
#include <cstddef>

#define N_NODES 50000
#define NEG_SLOPE 0.2f
#define NB 196            // buckets of 256 nodes: (50000+255)/256
#define BIN_CHUNK 8192    // edges per block in hist/bin kernels
#define SLICE_MAX 14336   // LDS slice capacity (mean ~4345, 3.3x headroom)

typedef float floatx4 __attribute__((ext_vector_type(4)));
typedef short shortx8 __attribute__((ext_vector_type(8)));

// ---- fp32 <-> bf16 helpers (RNE) --------------------------------------------
__device__ __forceinline__ unsigned short f2b(float f) {
    union { float f; unsigned u; } v; v.f = f;
    unsigned u = v.u;
    return (unsigned short)((u + 0x7FFFu + ((u >> 16) & 1u)) >> 16);
}
__device__ __forceinline__ float b2f(unsigned short b) {
    union { unsigned u; float f; } v; v.u = ((unsigned)b) << 16;
    return v.f;
}

// ---------------------------------------------------------------------------
// CSR build, bucketed multisplit.
// ---------------------------------------------------------------------------
__global__ __launch_bounds__(256) void bucket_hist_kernel(
    const int* __restrict__ ei, int E0, int E, int* __restrict__ bhist) {
    __shared__ int h[NB];
    int t = threadIdx.x;
    for (int i = t; i < NB; i += 256) h[i] = 0;
    __syncthreads();
    int base = blockIdx.x * BIN_CHUNK;
    int end = min(base + BIN_CHUNK, E);
    for (int e = base + t; e < end; e += 256) {
        int d = (e < E0) ? ei[E0 + e] : (e - E0);
        atomicAdd(&h[d >> 8], 1);
    }
    __syncthreads();
    for (int i = t; i < NB; i += 256)
        if (h[i]) atomicAdd(&bhist[i], h[i]);
}

__global__ __launch_bounds__(256) void bucket_scan_kernel(
    const int* __restrict__ bhist, int* __restrict__ bbase,
    int* __restrict__ bcursor, int* __restrict__ rowptr, int E) {
    __shared__ int buf[256];
    int t = threadIdx.x;
    int v = (t < NB) ? bhist[t] : 0;
    int x = v;
    for (int off = 1; off < 256; off <<= 1) {
        buf[t] = x; __syncthreads();
        int y = (t >= off) ? buf[t - off] : 0;
        __syncthreads();
        x += y;
    }
    if (t < NB) {
        bbase[t] = x - v;
        bcursor[t] = x - v;
    }
    if (t == NB - 1) bbase[NB] = x;
    if (t == 0) rowptr[N_NODES] = E;
}

__global__ __launch_bounds__(256) void bin_kernel(
    const int* __restrict__ ei, int E0, int E,
    int* __restrict__ bcursor, unsigned int* __restrict__ ebuf) {
    __shared__ int h[NB];
    __shared__ int gbase[NB];
    int t = threadIdx.x;
    for (int i = t; i < NB; i += 256) h[i] = 0;
    __syncthreads();
    int base = blockIdx.x * BIN_CHUNK;
    int end = min(base + BIN_CHUNK, E);
    for (int e = base + t; e < end; e += 256) {
        int d = (e < E0) ? ei[E0 + e] : (e - E0);
        atomicAdd(&h[d >> 8], 1);
    }
    __syncthreads();
    for (int i = t; i < NB; i += 256) {
        int c = h[i];
        gbase[i] = c ? atomicAdd(&bcursor[i], c) : 0;
        h[i] = 0;
    }
    __syncthreads();
    for (int e = base + t; e < end; e += 256) {
        int s, d;
        if (e < E0) { s = ei[e]; d = ei[E0 + e]; }
        else        { s = e - E0; d = e - E0; }
        int b = d >> 8;
        int off = atomicAdd(&h[b], 1);
        ebuf[gbase[b] + off] = (unsigned)s | ((unsigned)(d & 255) << 16);
    }
}

// K4: one block per bucket; emits rowptr, csr_src (int) and csr_dst (ushort)
__global__ __launch_bounds__(256) void build_kernel(
    const unsigned int* __restrict__ ebuf, const int* __restrict__ bbase,
    int* __restrict__ rowptr, int* __restrict__ csr_src,
    unsigned short* __restrict__ csr_dst) {
    __shared__ int h[256];
    __shared__ int lrp[257];
    __shared__ unsigned int stag[SLICE_MAX];
    int b = blockIdx.x, t = threadIdx.x;
    int e0 = bbase[b], e1 = bbase[b + 1];
    int cnt = e1 - e0;
    int n0 = b << 8;
    h[t] = 0;
    __syncthreads();
    for (int i = t; i < cnt; i += 256)
        atomicAdd(&h[ebuf[e0 + i] >> 16], 1);
    __syncthreads();
    int v = h[t], x = v;
    __shared__ int buf[256];
    for (int off = 1; off < 256; off <<= 1) {
        buf[t] = x; __syncthreads();
        int y = (t >= off) ? buf[t - off] : 0;
        __syncthreads();
        x += y;
    }
    lrp[t] = x - v;
    if (t == 255) lrp[256] = x;
    h[t] = 0;
    __syncthreads();
    int n = n0 + t;
    if (n < N_NODES) rowptr[n] = e0 + lrp[t];
    for (int i = t; i < cnt; i += 256) {
        unsigned int v2 = ebuf[e0 + i];
        int dloc = v2 >> 16;
        int off = atomicAdd(&h[dloc], 1);
        stag[lrp[dloc] + off] = v2;           // src | dloc<<16 (both <2^16)
    }
    __syncthreads();
    for (int i = t; i < cnt; i += 256) {
        unsigned int v2 = stag[i];
        csr_src[e0 + i] = (int)(v2 & 0xFFFFu);
        csr_dst[e0 + i] = (unsigned short)(n0 + (v2 >> 16));
    }
}

// ---------------------------------------------------------------------------
// Edge-major attention-weight precompute.
// ---------------------------------------------------------------------------
__global__ __launch_bounds__(256) void edge_w1_kernel(
    const int* __restrict__ csr_src, const unsigned short* __restrict__ csr_dst,
    const float* __restrict__ a_src, const float* __restrict__ a_dst,
    float* __restrict__ ew, int E) {
    int e = blockIdx.x * blockDim.x + threadIdx.x;
    if (e >= E) return;
    int s = csr_src[e];
    int d = csr_dst[e];
    float4 as = *(const float4*)&a_src[s << 2];
    float4 ad = *(const float4*)&a_dst[d << 2];
    float4 w;
    float l;
    l = as.x + ad.x; l = l > 0.f ? l : NEG_SLOPE * l; w.x = __expf(l);
    l = as.y + ad.y; l = l > 0.f ? l : NEG_SLOPE * l; w.y = __expf(l);
    l = as.z + ad.z; l = l > 0.f ? l : NEG_SLOPE * l; w.z = __expf(l);
    l = as.w + ad.w; l = l > 0.f ? l : NEG_SLOPE * l; w.w = __expf(l);
    *(float4*)&ew[(size_t)e << 2] = w;
}

__global__ __launch_bounds__(256) void edge_w2_kernel(
    const int* __restrict__ csr_src, const unsigned short* __restrict__ csr_dst,
    const float* __restrict__ a_src, const float* __restrict__ a_dst,
    float* __restrict__ ew, int E) {
    int e = blockIdx.x * blockDim.x + threadIdx.x;
    if (e >= E) return;
    float l = a_src[csr_src[e]] + a_dst[csr_dst[e]];
    l = l > 0.f ? l : NEG_SLOPE * l;
    ew[e] = __expf(l);
}

// ---------------------------------------------------------------------------
// Single-bf16 MFMA GEMM:  C[M,NREAL] = A[M,KK] x B[NREAL,KK]^T
// ---------------------------------------------------------------------------
template <int BM, int BN, int NREAL, int KK, typename InT, typename OutT>
__global__ __launch_bounds__(256) void gemm_bf16_kernel(
    const InT* __restrict__ A, const float* __restrict__ B,
    OutT* __restrict__ C, int M) {
    const int BK = 64, LDK = 72;
    const int NT = BN / 16;
    __shared__ unsigned short As[BM * LDK];
    __shared__ unsigned short Bs[BN * LDK];
    const int t = threadIdx.x;
    const int wave = t >> 6, lane = t & 63;
    const int lrow = lane & 15, lkg = lane >> 4;
    const int bm = blockIdx.x * BM;

    floatx4 acc[NT] = {};

    for (int k0 = 0; k0 < KK; k0 += BK) {
        __syncthreads();
        if constexpr (sizeof(InT) == 4) {
            for (int i = t; i < BM * 16; i += 256) {
                int r = i >> 4, c4 = (i & 15) << 2;
                int gr = bm + r;
                float4 v = make_float4(0.f, 0.f, 0.f, 0.f);
                if (gr < M) v = *(const float4*)&A[(size_t)gr * KK + k0 + c4];
                int o = r * LDK + c4;
                As[o] = f2b(v.x); As[o + 1] = f2b(v.y);
                As[o + 2] = f2b(v.z); As[o + 3] = f2b(v.w);
            }
        } else {
            for (int i = t; i < BM * 8; i += 256) {
                int r = i >> 3, c8 = (i & 7) << 3;
                int gr = bm + r;
                shortx8 v = {};
                if (gr < M) v = *(const shortx8*)&A[(size_t)gr * KK + k0 + c8];
                *(shortx8*)&As[r * LDK + c8] = v;
            }
        }
        for (int i = t; i < BN * 16; i += 256) {
            int r = i >> 4, c4 = (i & 15) << 2;
            float4 v = make_float4(0.f, 0.f, 0.f, 0.f);
            if (r < NREAL) v = *(const float4*)&B[(size_t)r * KK + k0 + c4];
            int o = r * LDK + c4;
            Bs[o] = f2b(v.x); Bs[o + 1] = f2b(v.y);
            Bs[o + 2] = f2b(v.z); Bs[o + 3] = f2b(v.w);
        }
        __syncthreads();

        for (int ks = 0; ks < BK; ks += 32) {
            int kc = ks + lkg * 8;
            int row = wave * 16 + lrow;
            shortx8 a = *(const shortx8*)&As[row * LDK + kc];
#pragma unroll
            for (int nt = 0; nt < NT; nt++) {
                shortx8 b = *(const shortx8*)&Bs[(nt * 16 + lrow) * LDK + kc];
                acc[nt] = __builtin_amdgcn_mfma_f32_16x16x32_bf16(a, b, acc[nt], 0, 0, 0);
            }
        }
    }
#pragma unroll
    for (int nt = 0; nt < NT; nt++)
#pragma unroll
        for (int r = 0; r < 4; r++) {
            int row = bm + wave * 16 + lkg * 4 + r;
            int col = nt * 16 + lrow;
            if (row < M && col < NREAL) {
                if constexpr (sizeof(OutT) == 2)
                    C[(size_t)row * NREAL + col] = f2b(acc[nt][r]);
                else
                    C[(size_t)row * NREAL + col] = acc[nt][r];
            }
        }
}

// ---------------------------------------------------------------------------
// Attention coefficients
// ---------------------------------------------------------------------------
__global__ void att1_kernel(const unsigned short* __restrict__ h1b,
                            const float* __restrict__ att_src,
                            const float* __restrict__ att_dst,
                            float* __restrict__ a_src, float* __restrict__ a_dst,
                            int N) {
    int i = blockIdx.x * blockDim.x + threadIdx.x;
    if (i >= N * 4) return;
    int h = i & 3;
    const ushort4* hp = (const ushort4*)(h1b + (size_t)i * 32);
    const float4* as = (const float4*)(att_src + h * 32);
    const float4* ad = (const float4*)(att_dst + h * 32);
    float ssum = 0.f, dsum = 0.f;
#pragma unroll
    for (int j = 0; j < 8; j++) {
        ushort4 hv = hp[j];
        float4 av = as[j], dv = ad[j];
        float x0 = b2f(hv.x), x1 = b2f(hv.y), x2 = b2f(hv.z), x3 = b2f(hv.w);
        ssum += x0 * av.x + x1 * av.y + x2 * av.z + x3 * av.w;
        dsum += x0 * dv.x + x1 * dv.y + x2 * dv.z + x3 * dv.w;
    }
    a_src[i] = ssum;
    a_dst[i] = dsum;
}

// layer 2: h2 fp32 [N,40]
__global__ void att2_kernel(const float* __restrict__ h2,
                            const float* __restrict__ att_src,
                            const float* __restrict__ att_dst,
                            float* __restrict__ a_src, float* __restrict__ a_dst,
                            int N) {
    int n = blockIdx.x * blockDim.x + threadIdx.x;
    if (n >= N) return;
    const float4* hp = (const float4*)(h2 + (size_t)n * 40);
    const float4* as = (const float4*)att_src;
    const float4* ad = (const float4*)att_dst;
    float ssum = 0.f, dsum = 0.f;
#pragma unroll
    for (int j = 0; j < 10; j++) {
        float4 hv = hp[j];
        float4 av = as[j], dv = ad[j];
        ssum += hv.x * av.x + hv.y * av.y + hv.z * av.z + hv.w * av.w;
        dsum += hv.x * dv.x + hv.y * dv.y + hv.z * dv.z + hv.w * dv.w;
    }
    a_src[n] = ssum;
    a_dst[n] = dsum;
}

// ---------------------------------------------------------------------------
// Aggregation layer 1: one WAVE per node. Branch-free inner loop:
// zero-weight padding (s=0,w=0 for idx>=deg) instead of exec-mask guards.
// Lane = (quarter q = lane>>4, sub = lane&15): ushort8 16B gather -> 4 rows
// per wave instruction; lane covers dims sub*8..sub*8+7 (head = sub>>2).
// Quarter-partial accumulators; shfl_xor(16/32) reduce at the end.
// ---------------------------------------------------------------------------
__global__ __launch_bounds__(256) void agg1_kernel(
    const unsigned short* __restrict__ h1b, const float* __restrict__ ew,
    const int* __restrict__ rowptr, const int* __restrict__ csr_src,
    const float* __restrict__ b1, unsigned short* __restrict__ zb, int N) {
    int wave = threadIdx.x >> 6, lane = threadIdx.x & 63;
    int n = blockIdx.x * 4 + wave;
    if (n >= N) return;
    int q = lane >> 4, sub = lane & 15, headq = sub >> 2;
    int beg = rowptr[n], deg = rowptr[n + 1] - beg;

    floatx4 a0 = {0.f, 0.f, 0.f, 0.f}, a1 = {0.f, 0.f, 0.f, 0.f};
    float den = 0.f;
    for (int c0 = 0; c0 < deg; c0 += 16) {
        // preload 16 edges: lane j holds edge c0+(j>>2), head j&3
        int idx = c0 + (lane >> 2);
        int s_e = (idx < deg) ? csr_src[beg + idx] : 0;
        float w_e = (idx < deg) ? ew[((size_t)(beg + c0) << 2) + lane] : 0.f;
#pragma unroll
        for (int i = 0; i < 4; i++) {
            int eb = 4 * i + q;                        // edge slot 0..15
            int s = __shfl(s_e, eb << 2);
            float w = __shfl(w_e, (eb << 2) + headq);
            shortx8 v = *(const shortx8*)&h1b[((size_t)s << 7) + (sub << 3)];
            den += w;
            a0.x += w * b2f((unsigned short)v[0]);
            a0.y += w * b2f((unsigned short)v[1]);
            a0.z += w * b2f((unsigned short)v[2]);
            a0.w += w * b2f((unsigned short)v[3]);
            a1.x += w * b2f((unsigned short)v[4]);
            a1.y += w * b2f((unsigned short)v[5]);
            a1.z += w * b2f((unsigned short)v[6]);
            a1.w += w * b2f((unsigned short)v[7]);
        }
    }
    // reduce partial sums across quarters (lanes with equal sub)
#pragma unroll
    for (int off = 16; off <= 32; off <<= 1) {
        a0.x += __shfl_xor(a0.x, off); a0.y += __shfl_xor(a0.y, off);
        a0.z += __shfl_xor(a0.z, off); a0.w += __shfl_xor(a0.w, off);
        a1.x += __shfl_xor(a1.x, off); a1.y += __shfl_xor(a1.y, off);
        a1.z += __shfl_xor(a1.z, off); a1.w += __shfl_xor(a1.w, off);
        den  += __shfl_xor(den, off);
    }
    if (q == 0) {
        float inv = 1.f / den;
        float4 bb0 = *(const float4*)&b1[sub << 3];
        float4 bb1 = *(const float4*)&b1[(sub << 3) + 4];
        shortx8 r;
        r[0] = (short)f2b(fmaxf(a0.x * inv + bb0.x, 0.f));
        r[1] = (short)f2b(fmaxf(a0.y * inv + bb0.y, 0.f));
        r[2] = (short)f2b(fmaxf(a0.z * inv + bb0.z, 0.f));
        r[3] = (short)f2b(fmaxf(a0.w * inv + bb0.w, 0.f));
        r[4] = (short)f2b(fmaxf(a1.x * inv + bb1.x, 0.f));
        r[5] = (short)f2b(fmaxf(a1.y * inv + bb1.y, 0.f));
        r[6] = (short)f2b(fmaxf(a1.z * inv + bb1.z, 0.f));
        r[7] = (short)f2b(fmaxf(a1.w * inv + bb1.w, 0.f));
        *(shortx8*)&zb[((size_t)n << 7) + (sub << 3)] = r;
    }
}

// ---------------------------------------------------------------------------
// Aggregation layer 2: one wave per node, H=1, D=40, fp32 h2.
// Zero-weight padding; only static pos<20 lane predicate remains.
// ---------------------------------------------------------------------------
__global__ __launch_bounds__(256) void agg2_kernel(
    const float* __restrict__ h2, const float* __restrict__ ew,
    const int* __restrict__ rowptr, const int* __restrict__ csr_src,
    const float* __restrict__ b2, float* __restrict__ out, int N) {
    int wave = threadIdx.x >> 6, lane = threadIdx.x & 63;
    int n = blockIdx.x * 4 + wave;
    if (n >= N) return;
    int half = lane >> 5, pos = lane & 31;
    int beg = rowptr[n], deg = rowptr[n + 1] - beg;

    float2 acc = {0.f, 0.f};
    float den = 0.f;
    for (int c0 = 0; c0 < deg; c0 += 32) {
        int idx = c0 + (lane & 31);
        int s_e = (idx < deg) ? csr_src[beg + idx] : 0;
        float w_e = (idx < deg) ? ew[beg + idx] : 0.f;
#pragma unroll
        for (int e = 0; e < 32; e += 2) {
            int el = e + half;
            int s = __shfl(s_e, el);
            float w = __shfl(w_e, el);
            den += w;
            if (pos < 20) {
                float2 v = *(const float2*)&h2[(size_t)s * 40 + pos * 2];
                acc.x += w * v.x;
                acc.y += w * v.y;
            }
        }
    }
    acc.x += __shfl_xor(acc.x, 32);
    acc.y += __shfl_xor(acc.y, 32);
    den   += __shfl_xor(den, 32);
    if (half == 0 && pos < 20) {
        float inv = 1.f / den;
        float2 bb = *(const float2*)&b2[pos * 2];
        float2 o;
        o.x = acc.x * inv + bb.x;
        o.y = acc.y * inv + bb.y;
        *(float2*)&out[(size_t)n * 40 + pos * 2] = o;
    }
}

// ---------------------------------------------------------------------------
extern "C" void kernel_launch(void* const* d_in, const int* in_sizes, int n_in,
                              void* d_out, int out_size, void* d_ws, size_t ws_size,
                              hipStream_t stream) {
    const float* x        = (const float*)d_in[0];
    const int*   ei       = (const int*)d_in[1];
    const float* W1       = (const float*)d_in[2];
    const float* att_src1 = (const float*)d_in[3];
    const float* att_dst1 = (const float*)d_in[4];
    const float* b1       = (const float*)d_in[5];
    const float* W2       = (const float*)d_in[6];
    const float* att_src2 = (const float*)d_in[7];
    const float* att_dst2 = (const float*)d_in[8];
    const float* b2       = (const float*)d_in[9];
    float* out = (float*)d_out;

    const int N  = N_NODES;
    const int E0 = in_sizes[1] / 2;
    const int E  = E0 + N;
    const int NBLK = (E + BIN_CHUNK - 1) / BIN_CHUNK;

    char* ws = (char*)d_ws;
    unsigned short* h1b = (unsigned short*)(ws + 0);          // 12,800,000
    unsigned short* zb  = (unsigned short*)(ws + 12800000);   // 12,800,000
    float*          h2  = (float*)(ws + 25600000);            //  8,000,000 (fp32)
    float* a_src1 = (float*)(ws + 33600000);                  //    800,000
    float* a_dst1 = (float*)(ws + 34400000);                  //    800,000
    float* a_src2 = (float*)(ws + 35200000);                  //    200,000
    float* a_dst2 = (float*)(ws + 35400000);                  //    200,000
    int*   rowptr = (int*)(ws + 35600000);                    //    200,004
    int*   bhist  = (int*)(ws + 35800192);                    //        784
    int*   bbase  = (int*)(ws + 35801088);                    //        788
    int*   bcursor= (int*)(ws + 35801984);                    //        784
    unsigned int* ebuf = (unsigned int*)(ws + 35802880);      //  3,400,000
    int*   csr_src= (int*)(ws + 39202880);                    //  3,400,000
    unsigned short* csr_dst = (unsigned short*)(ws + 42602880); // 1,700,000
    float* ew1    = (float*)(ws + 44302880);                  // 13,600,000
    float* ew2    = (float*)(ws + 57902880);                  //  3,400,000
    // total ~61.3 MB

    hipMemsetAsync(bhist, 0, NB * sizeof(int), stream);

    bucket_hist_kernel<<<NBLK, 256, 0, stream>>>(ei, E0, E, bhist);
    bucket_scan_kernel<<<1, 256, 0, stream>>>(bhist, bbase, bcursor, rowptr, E);
    bin_kernel<<<NBLK, 256, 0, stream>>>(ei, E0, E, bcursor, ebuf);
    build_kernel<<<NB, 256, 0, stream>>>(ebuf, bbase, rowptr, csr_src, csr_dst);

    // layer 1
    gemm_bf16_kernel<64, 128, 128, 256, float, unsigned short>
        <<<(N + 63) / 64, 256, 0, stream>>>(x, W1, h1b, N);
    att1_kernel<<<(N * 4 + 255) / 256, 256, 0, stream>>>(h1b, att_src1, att_dst1, a_src1, a_dst1, N);
    edge_w1_kernel<<<(E + 255) / 256, 256, 0, stream>>>(csr_src, csr_dst, a_src1, a_dst1, ew1, E);
    agg1_kernel<<<(N + 3) / 4, 256, 0, stream>>>(h1b, ew1, rowptr, csr_src, b1, zb, N);

    // layer 2 (h2 fp32 for accuracy headroom)
    gemm_bf16_kernel<64, 48, 40, 128, unsigned short, float>
        <<<(N + 63) / 64, 256, 0, stream>>>(zb, W2, h2, N);
    att2_kernel<<<(N + 255) / 256, 256, 0, stream>>>(h2, att_src2, att_dst2, a_src2, a_dst2, N);
    edge_w2_kernel<<<(E + 255) / 256, 256, 0, stream>>>(csr_src, csr_dst, a_src2, a_dst2, ew2, E);
    agg2_kernel<<<(N + 3) / 4, 256, 0, stream>>>(h2, ew2, rowptr, csr_src, b2, out, N);
}

// Round 9
// 273.138 us; speedup vs baseline: 1.0291x; 1.0247x over previous
//
#include <hip/hip_runtime.h>
#include <hip/hip_bf16.h>
#include <cstdint>
#include <cstddef>

#define N_NODES 50000
#define NEG_SLOPE 0.2f
#define NB 196            // buckets of 256 nodes: (50000+255)/256
#define BIN_CHUNK 8192    // edges per block in hist/bin kernels
#define SLICE_MAX 14336   // LDS slice capacity (mean ~4345, 3.3x headroom)

typedef float floatx4 __attribute__((ext_vector_type(4)));
typedef short shortx8 __attribute__((ext_vector_type(8)));

// ---- fp32 <-> bf16 helpers (RNE) --------------------------------------------
__device__ __forceinline__ unsigned short f2b(float f) {
    union { float f; unsigned u; } v; v.f = f;
    unsigned u = v.u;
    return (unsigned short)((u + 0x7FFFu + ((u >> 16) & 1u)) >> 16);
}
__device__ __forceinline__ float b2f(unsigned short b) {
    union { unsigned u; float f; } v; v.u = ((unsigned)b) << 16;
    return v.f;
}

// ---------------------------------------------------------------------------
// CSR build, bucketed multisplit.
// ---------------------------------------------------------------------------
__global__ __launch_bounds__(256) void bucket_hist_kernel(
    const int* __restrict__ ei, int E0, int E, int* __restrict__ bhist) {
    __shared__ int h[NB];
    int t = threadIdx.x;
    for (int i = t; i < NB; i += 256) h[i] = 0;
    __syncthreads();
    int base = blockIdx.x * BIN_CHUNK;
    int end = min(base + BIN_CHUNK, E);
    for (int e = base + t; e < end; e += 256) {
        int d = (e < E0) ? ei[E0 + e] : (e - E0);
        atomicAdd(&h[d >> 8], 1);
    }
    __syncthreads();
    for (int i = t; i < NB; i += 256)
        if (h[i]) atomicAdd(&bhist[i], h[i]);
}

__global__ __launch_bounds__(256) void bucket_scan_kernel(
    const int* __restrict__ bhist, int* __restrict__ bbase,
    int* __restrict__ bcursor, int* __restrict__ rowptr, int E) {
    __shared__ int buf[256];
    int t = threadIdx.x;
    int v = (t < NB) ? bhist[t] : 0;
    int x = v;
    for (int off = 1; off < 256; off <<= 1) {
        buf[t] = x; __syncthreads();
        int y = (t >= off) ? buf[t - off] : 0;
        __syncthreads();
        x += y;
    }
    if (t < NB) {
        bbase[t] = x - v;
        bcursor[t] = x - v;
    }
    if (t == NB - 1) bbase[NB] = x;
    if (t == 0) rowptr[N_NODES] = E;
}

__global__ __launch_bounds__(256) void bin_kernel(
    const int* __restrict__ ei, int E0, int E,
    int* __restrict__ bcursor, unsigned int* __restrict__ ebuf) {
    __shared__ int h[NB];
    __shared__ int gbase[NB];
    int t = threadIdx.x;
    for (int i = t; i < NB; i += 256) h[i] = 0;
    __syncthreads();
    int base = blockIdx.x * BIN_CHUNK;
    int end = min(base + BIN_CHUNK, E);
    for (int e = base + t; e < end; e += 256) {
        int d = (e < E0) ? ei[E0 + e] : (e - E0);
        atomicAdd(&h[d >> 8], 1);
    }
    __syncthreads();
    for (int i = t; i < NB; i += 256) {
        int c = h[i];
        gbase[i] = c ? atomicAdd(&bcursor[i], c) : 0;
        h[i] = 0;
    }
    __syncthreads();
    for (int e = base + t; e < end; e += 256) {
        int s, d;
        if (e < E0) { s = ei[e]; d = ei[E0 + e]; }
        else        { s = e - E0; d = e - E0; }
        int b = d >> 8;
        int off = atomicAdd(&h[b], 1);
        ebuf[gbase[b] + off] = (unsigned)s | ((unsigned)(d & 255) << 16);
    }
}

// K4: one block per bucket; emits rowptr, csr_src (int) and csr_dst (ushort)
__global__ __launch_bounds__(256) void build_kernel(
    const unsigned int* __restrict__ ebuf, const int* __restrict__ bbase,
    int* __restrict__ rowptr, int* __restrict__ csr_src,
    unsigned short* __restrict__ csr_dst) {
    __shared__ int h[256];
    __shared__ int lrp[257];
    __shared__ unsigned int stag[SLICE_MAX];
    int b = blockIdx.x, t = threadIdx.x;
    int e0 = bbase[b], e1 = bbase[b + 1];
    int cnt = e1 - e0;
    int n0 = b << 8;
    h[t] = 0;
    __syncthreads();
    for (int i = t; i < cnt; i += 256)
        atomicAdd(&h[ebuf[e0 + i] >> 16], 1);
    __syncthreads();
    int v = h[t], x = v;
    __shared__ int buf[256];
    for (int off = 1; off < 256; off <<= 1) {
        buf[t] = x; __syncthreads();
        int y = (t >= off) ? buf[t - off] : 0;
        __syncthreads();
        x += y;
    }
    lrp[t] = x - v;
    if (t == 255) lrp[256] = x;
    h[t] = 0;
    __syncthreads();
    int n = n0 + t;
    if (n < N_NODES) rowptr[n] = e0 + lrp[t];
    for (int i = t; i < cnt; i += 256) {
        unsigned int v2 = ebuf[e0 + i];
        int dloc = v2 >> 16;
        int off = atomicAdd(&h[dloc], 1);
        stag[lrp[dloc] + off] = v2;           // src | dloc<<16 (both <2^16)
    }
    __syncthreads();
    for (int i = t; i < cnt; i += 256) {
        unsigned int v2 = stag[i];
        csr_src[e0 + i] = (int)(v2 & 0xFFFFu);
        csr_dst[e0 + i] = (unsigned short)(n0 + (v2 >> 16));
    }
}

// ---------------------------------------------------------------------------
// Edge-major attention-weight precompute.
// ---------------------------------------------------------------------------
__global__ __launch_bounds__(256) void edge_w1_kernel(
    const int* __restrict__ csr_src, const unsigned short* __restrict__ csr_dst,
    const float* __restrict__ a_src, const float* __restrict__ a_dst,
    float* __restrict__ ew, int E) {
    int e = blockIdx.x * blockDim.x + threadIdx.x;
    if (e >= E) return;
    int s = csr_src[e];
    int d = csr_dst[e];
    float4 as = *(const float4*)&a_src[s << 2];
    float4 ad = *(const float4*)&a_dst[d << 2];
    float4 w;
    float l;
    l = as.x + ad.x; l = l > 0.f ? l : NEG_SLOPE * l; w.x = __expf(l);
    l = as.y + ad.y; l = l > 0.f ? l : NEG_SLOPE * l; w.y = __expf(l);
    l = as.z + ad.z; l = l > 0.f ? l : NEG_SLOPE * l; w.z = __expf(l);
    l = as.w + ad.w; l = l > 0.f ? l : NEG_SLOPE * l; w.w = __expf(l);
    *(float4*)&ew[(size_t)e << 2] = w;
}

__global__ __launch_bounds__(256) void edge_w2_kernel(
    const int* __restrict__ csr_src, const unsigned short* __restrict__ csr_dst,
    const float* __restrict__ a_src, const float* __restrict__ a_dst,
    float* __restrict__ ew, int E) {
    int e = blockIdx.x * blockDim.x + threadIdx.x;
    if (e >= E) return;
    float l = a_src[csr_src[e]] + a_dst[csr_dst[e]];
    l = l > 0.f ? l : NEG_SLOPE * l;
    ew[e] = __expf(l);
}

// ---------------------------------------------------------------------------
// Single-bf16 MFMA GEMM:  C[M,NREAL] = A[M,KK] x B[NREAL,KK]^T
// ---------------------------------------------------------------------------
template <int BM, int BN, int NREAL, int KK, typename InT, typename OutT>
__global__ __launch_bounds__(256) void gemm_bf16_kernel(
    const InT* __restrict__ A, const float* __restrict__ B,
    OutT* __restrict__ C, int M) {
    const int BK = 64, LDK = 72;
    const int NT = BN / 16;
    __shared__ unsigned short As[BM * LDK];
    __shared__ unsigned short Bs[BN * LDK];
    const int t = threadIdx.x;
    const int wave = t >> 6, lane = t & 63;
    const int lrow = lane & 15, lkg = lane >> 4;
    const int bm = blockIdx.x * BM;

    floatx4 acc[NT] = {};

    for (int k0 = 0; k0 < KK; k0 += BK) {
        __syncthreads();
        if constexpr (sizeof(InT) == 4) {
            for (int i = t; i < BM * 16; i += 256) {
                int r = i >> 4, c4 = (i & 15) << 2;
                int gr = bm + r;
                float4 v = make_float4(0.f, 0.f, 0.f, 0.f);
                if (gr < M) v = *(const float4*)&A[(size_t)gr * KK + k0 + c4];
                int o = r * LDK + c4;
                As[o] = f2b(v.x); As[o + 1] = f2b(v.y);
                As[o + 2] = f2b(v.z); As[o + 3] = f2b(v.w);
            }
        } else {
            for (int i = t; i < BM * 8; i += 256) {
                int r = i >> 3, c8 = (i & 7) << 3;
                int gr = bm + r;
                shortx8 v = {};
                if (gr < M) v = *(const shortx8*)&A[(size_t)gr * KK + k0 + c8];
                *(shortx8*)&As[r * LDK + c8] = v;
            }
        }
        for (int i = t; i < BN * 16; i += 256) {
            int r = i >> 4, c4 = (i & 15) << 2;
            float4 v = make_float4(0.f, 0.f, 0.f, 0.f);
            if (r < NREAL) v = *(const float4*)&B[(size_t)r * KK + k0 + c4];
            int o = r * LDK + c4;
            Bs[o] = f2b(v.x); Bs[o + 1] = f2b(v.y);
            Bs[o + 2] = f2b(v.z); Bs[o + 3] = f2b(v.w);
        }
        __syncthreads();

        for (int ks = 0; ks < BK; ks += 32) {
            int kc = ks + lkg * 8;
            int row = wave * 16 + lrow;
            shortx8 a = *(const shortx8*)&As[row * LDK + kc];
#pragma unroll
            for (int nt = 0; nt < NT; nt++) {
                shortx8 b = *(const shortx8*)&Bs[(nt * 16 + lrow) * LDK + kc];
                acc[nt] = __builtin_amdgcn_mfma_f32_16x16x32_bf16(a, b, acc[nt], 0, 0, 0);
            }
        }
    }
#pragma unroll
    for (int nt = 0; nt < NT; nt++)
#pragma unroll
        for (int r = 0; r < 4; r++) {
            int row = bm + wave * 16 + lkg * 4 + r;
            int col = nt * 16 + lrow;
            if (row < M && col < NREAL) {
                if constexpr (sizeof(OutT) == 2)
                    C[(size_t)row * NREAL + col] = f2b(acc[nt][r]);
                else
                    C[(size_t)row * NREAL + col] = acc[nt][r];
            }
        }
}

// ---------------------------------------------------------------------------
// Attention coefficients
// ---------------------------------------------------------------------------
__global__ void att1_kernel(const unsigned short* __restrict__ h1b,
                            const float* __restrict__ att_src,
                            const float* __restrict__ att_dst,
                            float* __restrict__ a_src, float* __restrict__ a_dst,
                            int N) {
    int i = blockIdx.x * blockDim.x + threadIdx.x;
    if (i >= N * 4) return;
    int h = i & 3;
    const ushort4* hp = (const ushort4*)(h1b + (size_t)i * 32);
    const float4* as = (const float4*)(att_src + h * 32);
    const float4* ad = (const float4*)(att_dst + h * 32);
    float ssum = 0.f, dsum = 0.f;
#pragma unroll
    for (int j = 0; j < 8; j++) {
        ushort4 hv = hp[j];
        float4 av = as[j], dv = ad[j];
        float x0 = b2f(hv.x), x1 = b2f(hv.y), x2 = b2f(hv.z), x3 = b2f(hv.w);
        ssum += x0 * av.x + x1 * av.y + x2 * av.z + x3 * av.w;
        dsum += x0 * dv.x + x1 * dv.y + x2 * dv.z + x3 * dv.w;
    }
    a_src[i] = ssum;
    a_dst[i] = dsum;
}

// layer 2: h2b bf16 [N,40]
__global__ void att2_kernel(const unsigned short* __restrict__ h2b,
                            const float* __restrict__ att_src,
                            const float* __restrict__ att_dst,
                            float* __restrict__ a_src, float* __restrict__ a_dst,
                            int N) {
    int n = blockIdx.x * blockDim.x + threadIdx.x;
    if (n >= N) return;
    const ushort4* hp = (const ushort4*)(h2b + (size_t)n * 40);
    const float4* as = (const float4*)att_src;
    const float4* ad = (const float4*)att_dst;
    float ssum = 0.f, dsum = 0.f;
#pragma unroll
    for (int j = 0; j < 10; j++) {
        ushort4 hv = hp[j];
        float4 av = as[j], dv = ad[j];
        float x0 = b2f(hv.x), x1 = b2f(hv.y), x2 = b2f(hv.z), x3 = b2f(hv.w);
        ssum += x0 * av.x + x1 * av.y + x2 * av.z + x3 * av.w;
        dsum += x0 * dv.x + x1 * dv.y + x2 * dv.z + x3 * dv.w;
    }
    a_src[n] = ssum;
    a_dst[n] = dsum;
}

// ---------------------------------------------------------------------------
// Aggregation layer 1: one WAVE per node. Branch-free inner loop:
// zero-weight padding (s=0,w=0 for idx>=deg) instead of exec-mask guards.
// Lane = (quarter q = lane>>4, sub = lane&15): ushort8 16B gather -> 4 rows
// per wave instruction; lane covers dims sub*8..sub*8+7 (head = sub>>2).
// ---------------------------------------------------------------------------
__global__ __launch_bounds__(256) void agg1_kernel(
    const unsigned short* __restrict__ h1b, const float* __restrict__ ew,
    const int* __restrict__ rowptr, const int* __restrict__ csr_src,
    const float* __restrict__ b1, unsigned short* __restrict__ zb, int N) {
    int wave = threadIdx.x >> 6, lane = threadIdx.x & 63;
    int n = blockIdx.x * 4 + wave;
    if (n >= N) return;
    int q = lane >> 4, sub = lane & 15, headq = sub >> 2;
    int beg = rowptr[n], deg = rowptr[n + 1] - beg;

    floatx4 a0 = {0.f, 0.f, 0.f, 0.f}, a1 = {0.f, 0.f, 0.f, 0.f};
    float den = 0.f;
    for (int c0 = 0; c0 < deg; c0 += 16) {
        int idx = c0 + (lane >> 2);
        int s_e = (idx < deg) ? csr_src[beg + idx] : 0;
        float w_e = (idx < deg) ? ew[((size_t)(beg + c0) << 2) + lane] : 0.f;
#pragma unroll
        for (int i = 0; i < 4; i++) {
            int eb = 4 * i + q;
            int s = __shfl(s_e, eb << 2);
            float w = __shfl(w_e, (eb << 2) + headq);
            shortx8 v = *(const shortx8*)&h1b[((size_t)s << 7) + (sub << 3)];
            den += w;
            a0.x += w * b2f((unsigned short)v[0]);
            a0.y += w * b2f((unsigned short)v[1]);
            a0.z += w * b2f((unsigned short)v[2]);
            a0.w += w * b2f((unsigned short)v[3]);
            a1.x += w * b2f((unsigned short)v[4]);
            a1.y += w * b2f((unsigned short)v[5]);
            a1.z += w * b2f((unsigned short)v[6]);
            a1.w += w * b2f((unsigned short)v[7]);
        }
    }
#pragma unroll
    for (int off = 16; off <= 32; off <<= 1) {
        a0.x += __shfl_xor(a0.x, off); a0.y += __shfl_xor(a0.y, off);
        a0.z += __shfl_xor(a0.z, off); a0.w += __shfl_xor(a0.w, off);
        a1.x += __shfl_xor(a1.x, off); a1.y += __shfl_xor(a1.y, off);
        a1.z += __shfl_xor(a1.z, off); a1.w += __shfl_xor(a1.w, off);
        den  += __shfl_xor(den, off);
    }
    if (q == 0) {
        float inv = 1.f / den;
        float4 bb0 = *(const float4*)&b1[sub << 3];
        float4 bb1 = *(const float4*)&b1[(sub << 3) + 4];
        shortx8 r;
        r[0] = (short)f2b(fmaxf(a0.x * inv + bb0.x, 0.f));
        r[1] = (short)f2b(fmaxf(a0.y * inv + bb0.y, 0.f));
        r[2] = (short)f2b(fmaxf(a0.z * inv + bb0.z, 0.f));
        r[3] = (short)f2b(fmaxf(a0.w * inv + bb0.w, 0.f));
        r[4] = (short)f2b(fmaxf(a1.x * inv + bb1.x, 0.f));
        r[5] = (short)f2b(fmaxf(a1.y * inv + bb1.y, 0.f));
        r[6] = (short)f2b(fmaxf(a1.z * inv + bb1.z, 0.f));
        r[7] = (short)f2b(fmaxf(a1.w * inv + bb1.w, 0.f));
        *(shortx8*)&zb[((size_t)n << 7) + (sub << 3)] = r;
    }
}

// ---------------------------------------------------------------------------
// Aggregation layer 2: one wave per node, H=1, D=40, bf16 h2b (4 MB — fits
// per-XCD L2; fp32 h2 was 8 MB and thrashed it). fp32 accumulate + fp32 out.
// ---------------------------------------------------------------------------
__global__ __launch_bounds__(256) void agg2_kernel(
    const unsigned short* __restrict__ h2b, const float* __restrict__ ew,
    const int* __restrict__ rowptr, const int* __restrict__ csr_src,
    const float* __restrict__ b2, float* __restrict__ out, int N) {
    int wave = threadIdx.x >> 6, lane = threadIdx.x & 63;
    int n = blockIdx.x * 4 + wave;
    if (n >= N) return;
    int half = lane >> 5, pos = lane & 31;
    int beg = rowptr[n], deg = rowptr[n + 1] - beg;

    float2 acc = {0.f, 0.f};
    float den = 0.f;
    for (int c0 = 0; c0 < deg; c0 += 32) {
        int idx = c0 + (lane & 31);
        int s_e = (idx < deg) ? csr_src[beg + idx] : 0;
        float w_e = (idx < deg) ? ew[beg + idx] : 0.f;
#pragma unroll
        for (int e = 0; e < 32; e += 2) {
            int el = e + half;
            int s = __shfl(s_e, el);
            float w = __shfl(w_e, el);
            den += w;
            if (pos < 20) {
                ushort2 v = *(const ushort2*)&h2b[(size_t)s * 40 + pos * 2];
                acc.x += w * b2f(v.x);
                acc.y += w * b2f(v.y);
            }
        }
    }
    acc.x += __shfl_xor(acc.x, 32);
    acc.y += __shfl_xor(acc.y, 32);
    den   += __shfl_xor(den, 32);
    if (half == 0 && pos < 20) {
        float inv = 1.f / den;
        float2 bb = *(const float2*)&b2[pos * 2];
        float2 o;
        o.x = acc.x * inv + bb.x;
        o.y = acc.y * inv + bb.y;
        *(float2*)&out[(size_t)n * 40 + pos * 2] = o;
    }
}

// ---------------------------------------------------------------------------
extern "C" void kernel_launch(void* const* d_in, const int* in_sizes, int n_in,
                              void* d_out, int out_size, void* d_ws, size_t ws_size,
                              hipStream_t stream) {
    const float* x        = (const float*)d_in[0];
    const int*   ei       = (const int*)d_in[1];
    const float* W1       = (const float*)d_in[2];
    const float* att_src1 = (const float*)d_in[3];
    const float* att_dst1 = (const float*)d_in[4];
    const float* b1       = (const float*)d_in[5];
    const float* W2       = (const float*)d_in[6];
    const float* att_src2 = (const float*)d_in[7];
    const float* att_dst2 = (const float*)d_in[8];
    const float* b2       = (const float*)d_in[9];
    float* out = (float*)d_out;

    const int N  = N_NODES;
    const int E0 = in_sizes[1] / 2;
    const int E  = E0 + N;
    const int NBLK = (E + BIN_CHUNK - 1) / BIN_CHUNK;

    char* ws = (char*)d_ws;
    unsigned short* h1b = (unsigned short*)(ws + 0);          // 12,800,000
    unsigned short* zb  = (unsigned short*)(ws + 12800000);   // 12,800,000
    unsigned short* h2b = (unsigned short*)(ws + 25600000);   //  4,000,000
    float* a_src1 = (float*)(ws + 29600000);                  //    800,000
    float* a_dst1 = (float*)(ws + 30400000);                  //    800,000
    float* a_src2 = (float*)(ws + 31200000);                  //    200,000
    float* a_dst2 = (float*)(ws + 31400000);                  //    200,000
    int*   rowptr = (int*)(ws + 31600000);                    //    200,004
    int*   bhist  = (int*)(ws + 31800192);                    //        784
    int*   bbase  = (int*)(ws + 31801088);                    //        788
    int*   bcursor= (int*)(ws + 31801984);                    //        784
    unsigned int* ebuf = (unsigned int*)(ws + 31802880);      //  3,400,000
    int*   csr_src= (int*)(ws + 35202880);                    //  3,400,000
    unsigned short* csr_dst = (unsigned short*)(ws + 38602880); // 1,700,000
    float* ew1    = (float*)(ws + 40302880);                  // 13,600,000
    float* ew2    = (float*)(ws + 53902880);                  //  3,400,000
    // total ~57.3 MB

    hipMemsetAsync(bhist, 0, NB * sizeof(int), stream);

    bucket_hist_kernel<<<NBLK, 256, 0, stream>>>(ei, E0, E, bhist);
    bucket_scan_kernel<<<1, 256, 0, stream>>>(bhist, bbase, bcursor, rowptr, E);
    bin_kernel<<<NBLK, 256, 0, stream>>>(ei, E0, E, bcursor, ebuf);
    build_kernel<<<NB, 256, 0, stream>>>(ebuf, bbase, rowptr, csr_src, csr_dst);

    // layer 1
    gemm_bf16_kernel<64, 128, 128, 256, float, unsigned short>
        <<<(N + 63) / 64, 256, 0, stream>>>(x, W1, h1b, N);
    att1_kernel<<<(N * 4 + 255) / 256, 256, 0, stream>>>(h1b, att_src1, att_dst1, a_src1, a_dst1, N);
    edge_w1_kernel<<<(E + 255) / 256, 256, 0, stream>>>(csr_src, csr_dst, a_src1, a_dst1, ew1, E);
    agg1_kernel<<<(N + 3) / 4, 256, 0, stream>>>(h1b, ew1, rowptr, csr_src, b1, zb, N);

    // layer 2 (h2b bf16: 4 MB gather table fits per-XCD L2)
    gemm_bf16_kernel<64, 48, 40, 128, unsigned short, unsigned short>
        <<<(N + 63) / 64, 256, 0, stream>>>(zb, W2, h2b, N);
    att2_kernel<<<(N + 255) / 256, 256, 0, stream>>>(h2b, att_src2, att_dst2, a_src2, a_dst2, N);
    edge_w2_kernel<<<(E + 255) / 256, 256, 0, stream>>>(csr_src, csr_dst, a_src2, a_dst2, ew2, E);
    agg2_kernel<<<(N + 3) / 4, 256, 0, stream>>>(h2b, ew2, rowptr, csr_src, b2, out, N);
}